// Round 5
// baseline (194.414 us; speedup 1.0000x reference)
//
#include <hip/hip_runtime.h>
#include <hip/hip_bf16.h>

typedef __attribute__((ext_vector_type(8))) unsigned short ushort8;
typedef __attribute__((ext_vector_type(8))) __bf16 bf16x8;
typedef __attribute__((ext_vector_type(4))) float f32x4;
typedef __attribute__((ext_vector_type(4))) float floatx4;

__device__ __forceinline__ unsigned short f2bf(float f) {
    unsigned u = __builtin_bit_cast(unsigned, f);
    u += 0x7fffu + ((u >> 16) & 1u);   // RNE
    return (unsigned short)(u >> 16);
}
__device__ __forceinline__ float bf2f(unsigned short h) {
    unsigned u = ((unsigned)h) << 16;
    return __builtin_bit_cast(float, u);
}

__device__ __forceinline__ void gload_lds16(const void* g, void* l) {
    __builtin_amdgcn_global_load_lds(
        (const __attribute__((address_space(1))) void*)g,
        (__attribute__((address_space(3))) void*)l,
        16, 0, 0);
}

#define BAR()   asm volatile("s_barrier" ::: "memory")
#define VMW(n)  asm volatile("s_waitcnt vmcnt(" #n ")" ::: "memory")
#define LGK(n)  asm volatile("s_waitcnt lgkmcnt(" #n ")" ::: "memory")

// ---------------- f32 -> bf16 conversion (8 elems/thread) ----------------
__global__ __launch_bounds__(256) void cvt_f2bf(const float* __restrict__ in,
                                                unsigned short* __restrict__ out,
                                                int n8) {
    int i = blockIdx.x * 256 + threadIdx.x;
    if (i >= n8) return;
    floatx4 a = ((const floatx4*)in)[2 * i];
    floatx4 b = ((const floatx4*)in)[2 * i + 1];
    ushort8 o;
#pragma unroll
    for (int j = 0; j < 4; ++j) { o[j] = f2bf(a[j]); o[4 + j] = f2bf(b[j]); }
    ((ushort8*)out)[i] = o;
}

// ---- Weff[o][j] = g[j]*fcW[o][j] + g[j+2048]*fcW[o][j+2048] (bf16) -------
// cc[o]   = fc_b[o] + sum_j ln_b[j]*fcW[o][j] + ln_b[j+2048]*fcW[o][j+2048]
// wsum[o] = sum_j bf16(Weff[o][j])   (sum of the ROUNDED values)
__global__ __launch_bounds__(256) void weff_kernel(const float* __restrict__ fcW,
                                                   const float* __restrict__ lng,
                                                   const float* __restrict__ lnb,
                                                   const float* __restrict__ fcb,
                                                   unsigned short* __restrict__ weff,
                                                   float* __restrict__ cc,
                                                   float* __restrict__ wsum) {
    int o = blockIdx.x;
    int tid = threadIdx.x;
    if (o >= 1000) {
        ushort8 z = {0, 0, 0, 0, 0, 0, 0, 0};
        ((ushort8*)(weff + (size_t)o * 2048))[tid] = z;
        if (tid == 0) { cc[o] = 0.f; wsum[o] = 0.f; }
        return;
    }
    const float* wrow = fcW + (size_t)o * 4096;
    int j0 = tid * 8;
    floatx4 wa  = *(const floatx4*)(wrow + j0);
    floatx4 wb  = *(const floatx4*)(wrow + j0 + 4);
    floatx4 wa2 = *(const floatx4*)(wrow + 2048 + j0);
    floatx4 wb2 = *(const floatx4*)(wrow + 2048 + j0 + 4);
    floatx4 ga  = *(const floatx4*)(lng + j0);
    floatx4 gb  = *(const floatx4*)(lng + j0 + 4);
    floatx4 ga2 = *(const floatx4*)(lng + 2048 + j0);
    floatx4 gb2 = *(const floatx4*)(lng + 2048 + j0 + 4);
    floatx4 ba  = *(const floatx4*)(lnb + j0);
    floatx4 bb  = *(const floatx4*)(lnb + j0 + 4);
    floatx4 ba2 = *(const floatx4*)(lnb + 2048 + j0);
    floatx4 bb2 = *(const floatx4*)(lnb + 2048 + j0 + 4);
    ushort8 o8;
    float acc = 0.f, ws = 0.f;
#pragma unroll
    for (int j = 0; j < 4; ++j) {
        o8[j] = f2bf(ga[j] * wa[j] + ga2[j] * wa2[j]);
        acc += ba[j] * wa[j] + ba2[j] * wa2[j];
        ws  += bf2f(o8[j]);
        o8[4 + j] = f2bf(gb[j] * wb[j] + gb2[j] * wb2[j]);
        acc += bb[j] * wb[j] + bb2[j] * wb2[j];
        ws  += bf2f(o8[4 + j]);
    }
    ((ushort8*)(weff + (size_t)o * 2048))[tid] = o8;
#pragma unroll
    for (int d = 32; d; d >>= 1) { acc += __shfl_down(acc, d); ws += __shfl_down(ws, d); }
    __shared__ float red[4], redw[4];
    if ((tid & 63) == 0) { red[tid >> 6] = acc; redw[tid >> 6] = ws; }
    __syncthreads();
    if (tid == 0) {
        cc[o] = fcb[o] + red[0] + red[1] + red[2] + red[3];
        wsum[o] = redw[0] + redw[1] + redw[2] + redw[3];
    }
}

// -------- row LN stats: mur[row] = {mu, rsqrt(var+eps)} over h2 row -------
__global__ __launch_bounds__(256) void ln_stats(const unsigned short* __restrict__ h2,
                                                float2* __restrict__ mur) {
    int row = blockIdx.x, tid = threadIdx.x;
    ushort8 v = ((const ushort8*)(h2 + (size_t)row * 2048))[tid];
    float s = 0.f, s2 = 0.f;
#pragma unroll
    for (int j = 0; j < 8; ++j) { float f = bf2f(v[j]); s += f; s2 += f * f; }
#pragma unroll
    for (int d = 32; d; d >>= 1) { s += __shfl_down(s, d); s2 += __shfl_down(s2, d); }
    __shared__ float rs_[4], rs2_[4];
    if ((tid & 63) == 0) { rs_[tid >> 6] = s; rs2_[tid >> 6] = s2; }
    __syncthreads();
    if (tid == 0) {
        float S = rs_[0] + rs_[1] + rs_[2] + rs_[3];
        float S2 = rs2_[0] + rs2_[1] + rs2_[2] + rs2_[3];
        float mu = S * (1.f / 2048.f);
        float var = S2 * (1.f / 2048.f) - mu * mu;
        mur[row] = make_float2(mu, rsqrtf(var + 1e-5f));
    }
}

// ==== pipelined bf16 GEMM: C[M,N] = A[M,K]*B[N,K]^T, BK=32, 4 LDS bufs ====
// BM=128, BN=64*NJ, 512 threads (8 waves 2M x 4N), per-wave C = 64 x 16*NJ.
// Register-double-buffered fragments: MFMA(t) from one set while ds_reads
// for tile t+1 fill the other (no lgkm stall in steady state). Stage depth 3.
// XOR swizzle for 64B rows: byte ^= (row&3)<<4 (both sides).
// EPI 0: bf16 out = tanh(acc + bias0[n] + bias1[n]), stride N
// EPI 1: f32 out = mur[row].y*(acc - mur[row].x*wsum[col]) + bias0[col]
template <int EPI, int NJ>
__global__ __launch_bounds__(512, 2) void gemm_p2(const unsigned short* __restrict__ A,
                                                  const unsigned short* __restrict__ B,
                                                  int M, int N, int K,
                                                  const float* __restrict__ bias0,
                                                  const float* __restrict__ bias1,
                                                  void* __restrict__ Cout, int ncols,
                                                  const float2* __restrict__ mur,
                                                  const float* __restrict__ wsum) {
    extern __shared__ char smem[];
    constexpr int BUFSZ = 8192 + NJ * 4096;   // A (8KB) + B (NJ*4KB), BK=32
    const int tid = threadIdx.x;
    const int lane = tid & 63, wid = tid >> 6;
    const int wm = wid >> 2, wn = wid & 3;      // 2 x 4 wave grid
    const int fr = lane & 15, g = lane >> 4;

    // XCD-aware bijective swizzle (nwg % 8 == 0 for all our launches)
    const int nwg = gridDim.x * gridDim.y;
    const int fid = blockIdx.y * gridDim.x + blockIdx.x;
    const int cpx = nwg >> 3;
    const int sw = (fid & 7) * cpx + (fid >> 3);
    const int bx = sw % gridDim.x, by = sw / gridDim.x;
    const int row0 = by * 128, col0 = bx * (64 * NJ);

    // staging: thread t -> dest byte t*16 (linear); row = t>>2 (64B rows),
    // source col pre-swizzled: byte ^= (row&3)<<4 (involution)
    const int srow = tid >> 2;
    const int scole = (((tid & 3) << 4) ^ ((srow & 3) << 4)) >> 1;  // elems

    auto stage = [&](int kt, char* buf) {
        gload_lds16(A + (size_t)(row0 + srow) * K + kt * 32 + scole, buf + tid * 16);
#pragma unroll
        for (int rr = 0; rr < NJ / 2; ++rr)
            gload_lds16(B + (size_t)(col0 + rr * 128 + srow) * K + kt * 32 + scole,
                        buf + 8192 + rr * 8192 + tid * 16);
    };

    const int kbyte = (g * 16) ^ ((fr & 3) << 4);
    auto readFrags = [&](bf16x8 (&fa)[4], bf16x8 (&fb)[NJ], const char* buf) {
#pragma unroll
        for (int m = 0; m < 4; ++m)
            fa[m] = __builtin_bit_cast(bf16x8,
                *(const ushort8*)(buf + (wm * 64 + m * 16 + fr) * 64 + kbyte));
#pragma unroll
        for (int n = 0; n < NJ; ++n)
            fb[n] = __builtin_bit_cast(bf16x8,
                *(const ushort8*)(buf + 8192 + (wn * (16 * NJ) + n * 16 + fr) * 64 + kbyte));
    };

    f32x4 acc[4][NJ];
#pragma unroll
    for (int i = 0; i < 4; ++i)
#pragma unroll
        for (int j = 0; j < NJ; ++j) acc[i][j] = f32x4{0.f, 0.f, 0.f, 0.f};

    auto domfma = [&](bf16x8 (&fa)[4], bf16x8 (&fb)[NJ]) {
        __builtin_amdgcn_s_setprio(1);
#pragma unroll
        for (int m = 0; m < 4; ++m)
#pragma unroll
            for (int n = 0; n < NJ; ++n)
                acc[m][n] = __builtin_amdgcn_mfma_f32_16x16x32_bf16(fa[m], fb[n], acc[m][n], 0, 0, 0);
        __builtin_amdgcn_s_setprio(0);
    };

    auto waitL = [&]() { if constexpr (NJ == 4) VMW(3); else VMW(2); };
    auto guard = [&]() { if constexpr (NJ == 4) LGK(8); else LGK(6); };

    char* q0 = smem;
    char* q1 = smem + BUFSZ;
    char* q2 = smem + 2 * BUFSZ;
    char* q3 = smem + 3 * BUFSZ;

    bf16x8 faA[4], fbA[NJ], faB[4], fbB[NJ];

    // prologue: stage tiles 0,1,2; read frags(0)
    stage(0, q0); stage(1, q1); stage(2, q2);
    if constexpr (NJ == 4) VMW(6); else VMW(4);   // S0 landed (own portion)
    BAR();
    readFrags(faA, fbA, q0);

    const int NT = K >> 5;
    for (int t = 0; t < NT; t += 2) {
        // ---- half A: MFMA tile t (set A); read frags(t+1) -> set B ----
        if (t + 2 < NT) waitL(); else VMW(0);   // S(t+1) landed
        guard();                                 // stale reads of buf(t-1) done
        BAR();
        if (t + 3 < NT) stage(t + 3, q3);
        readFrags(faB, fbB, q1);
        domfma(faA, fbA);
        { char* tmp = q0; q0 = q1; q1 = q2; q2 = q3; q3 = tmp; }

        // ---- half B: MFMA tile t+1 (set B); read frags(t+2) -> set A ----
        if (t + 3 < NT) waitL(); else VMW(0);   // S(t+2) landed
        guard();
        BAR();
        if (t + 4 < NT) stage(t + 4, q3);
        if (t + 2 < NT) readFrags(faA, fbA, q1);
        domfma(faB, fbB);
        { char* tmp = q0; q0 = q1; q1 = q2; q2 = q3; q3 = tmp; }
    }

    // ---- epilogue ----
#pragma unroll
    for (int i = 0; i < 4; ++i) {
        int rbase = row0 + wm * 64 + i * 16 + g * 4;
        if (EPI == 0) {
#pragma unroll
            for (int j = 0; j < NJ; ++j) {
                int col = col0 + wn * (16 * NJ) + j * 16 + fr;
                float bsum = bias0[col] + bias1[col];
                unsigned short* O = (unsigned short*)Cout;
#pragma unroll
                for (int r = 0; r < 4; ++r)
                    O[(size_t)(rbase + r) * N + col] = f2bf(tanhf(acc[i][j][r] + bsum));
            }
        } else {
            float2 mr[4];
#pragma unroll
            for (int r = 0; r < 4; ++r) mr[r] = mur[rbase + r];
#pragma unroll
            for (int j = 0; j < NJ; ++j) {
                int col = col0 + wn * (16 * NJ) + j * 16 + fr;
                if (col < ncols) {
                    float ws = wsum[col];
                    float ccv = bias0[col];
                    float* O = (float*)Cout;
#pragma unroll
                    for (int r = 0; r < 4; ++r)
                        O[(size_t)(rbase + r) * ncols + col] =
                            mr[r].y * (acc[i][j][r] - mr[r].x * ws) + ccv;
                }
            }
        }
    }
}

extern "C" void kernel_launch(void* const* d_in, const int* in_sizes, int n_in,
                              void* d_out, int out_size, void* d_ws, size_t ws_size,
                              hipStream_t stream) {
    const float* x   = (const float*)d_in[0];
    const float* W0  = (const float*)d_in[1];
    const float* bi0 = (const float*)d_in[2];
    const float* bh0 = (const float*)d_in[3];
    const float* W1  = (const float*)d_in[4];
    const float* bi1 = (const float*)d_in[5];
    const float* bh1 = (const float*)d_in[6];
    const float* lng = (const float*)d_in[7];
    const float* lnb = (const float*)d_in[8];
    const float* fcW = (const float*)d_in[9];
    const float* fcb = (const float*)d_in[10];
    float* out = (float*)d_out;

    char* w = (char*)d_ws;
    unsigned short* xb   = (unsigned short*)(w);                  // 4096x4096 bf16
    unsigned short* w0b  = (unsigned short*)(w + 33554432ull);    // 2048x4096 bf16
    unsigned short* w1b  = (unsigned short*)(w + 50331648ull);    // 2048x2048 bf16
    unsigned short* h1   = (unsigned short*)(w + 58720256ull);    // 4096x2048 bf16
    unsigned short* h2   = (unsigned short*)(w + 75497472ull);    // 4096x2048 bf16
    unsigned short* weff = (unsigned short*)(w + 92274688ull);    // 1024x2048 bf16
    float* cc            = (float*)(w + 96468992ull);             // 1024 f32
    float* wsum          = (float*)(w + 96473088ull);             // 1024 f32
    float2* mur          = (float2*)(w + 96477184ull);            // 4096 float2

    const int SHM0 = 4 * (8192 + 4 * 4096);  // 98304
    const int SHM1 = 4 * (8192 + 2 * 4096);  // 65536
    (void)hipFuncSetAttribute((const void*)gemm_p2<0, 4>,
                              hipFuncAttributeMaxDynamicSharedMemorySize, SHM0);
    (void)hipFuncSetAttribute((const void*)gemm_p2<1, 2>,
                              hipFuncAttributeMaxDynamicSharedMemorySize, SHM1);

    cvt_f2bf<<<8192, 256, 0, stream>>>(x,  xb,  2097152);
    cvt_f2bf<<<4096, 256, 0, stream>>>(W0, w0b, 1048576);
    cvt_f2bf<<<2048, 256, 0, stream>>>(W1, w1b, 524288);
    weff_kernel<<<1024, 256, 0, stream>>>(fcW, lng, lnb, fcb, weff, cc, wsum);
    // h1 = tanh(x @ W0^T + b_ih0 + b_hh0)
    gemm_p2<0, 4><<<dim3(8, 32), 512, SHM0, stream>>>(xb, w0b, 4096, 2048, 4096,
                                                      bi0, bh0, h1, 2048, nullptr, nullptr);
    // h2 = tanh(h1 @ W1^T + b_ih1 + b_hh1)
    gemm_p2<0, 4><<<dim3(8, 32), 512, SHM0, stream>>>(h1, w1b, 4096, 2048, 2048,
                                                      bi1, bh1, h2, 2048, nullptr, nullptr);
    // per-row LN stats of h2 (concat duplicates -> stats over h2 row)
    ln_stats<<<4096, 256, 0, stream>>>(h2, mur);
    // out = r*(h2 @ Weff^T - mu*wsum) + cc   (LN folded into epilogue)
    gemm_p2<1, 2><<<dim3(8, 32), 512, SHM1, stream>>>(h2, weff, 4096, 1024, 2048,
                                                      cc, nullptr, out, 1000, mur, wsum);
}

// Round 6
// 174.751 us; speedup vs baseline: 1.1125x; 1.1125x over previous
//
#include <hip/hip_runtime.h>
#include <hip/hip_bf16.h>

typedef __attribute__((ext_vector_type(8))) unsigned short ushort8;
typedef __attribute__((ext_vector_type(8))) __bf16 bf16x8;
typedef __attribute__((ext_vector_type(4))) float f32x4;
typedef __attribute__((ext_vector_type(4))) float floatx4;

__device__ __forceinline__ unsigned short f2bf(float f) {
    unsigned u = __builtin_bit_cast(unsigned, f);
    u += 0x7fffu + ((u >> 16) & 1u);   // RNE
    return (unsigned short)(u >> 16);
}
__device__ __forceinline__ float bf2f(unsigned short h) {
    unsigned u = ((unsigned)h) << 16;
    return __builtin_bit_cast(float, u);
}

__device__ __forceinline__ void gload_lds16(const void* g, void* l) {
    __builtin_amdgcn_global_load_lds(
        (const __attribute__((address_space(1))) void*)g,
        (__attribute__((address_space(3))) void*)l,
        16, 0, 0);
}

#define BAR()   asm volatile("s_barrier" ::: "memory")
#define VMW(n)  asm volatile("s_waitcnt vmcnt(" #n ")" ::: "memory")

// ---------------- f32 -> bf16 conversion (8 elems/thread) ----------------
__global__ __launch_bounds__(256) void cvt_f2bf(const float* __restrict__ in,
                                                unsigned short* __restrict__ out,
                                                int n8) {
    int i = blockIdx.x * 256 + threadIdx.x;
    if (i >= n8) return;
    floatx4 a = ((const floatx4*)in)[2 * i];
    floatx4 b = ((const floatx4*)in)[2 * i + 1];
    ushort8 o;
#pragma unroll
    for (int j = 0; j < 4; ++j) { o[j] = f2bf(a[j]); o[4 + j] = f2bf(b[j]); }
    ((ushort8*)out)[i] = o;
}

// ---- Weff[o][j] = g[j]*fcW[o][j] + g[j+2048]*fcW[o][j+2048] (bf16) -------
// cc[o]   = fc_b[o] + sum_j ln_b[j]*fcW[o][j] + ln_b[j+2048]*fcW[o][j+2048]
// wsum[o] = sum_j bf16(Weff[o][j])   (sum of the ROUNDED values)
__global__ __launch_bounds__(256) void weff_kernel(const float* __restrict__ fcW,
                                                   const float* __restrict__ lng,
                                                   const float* __restrict__ lnb,
                                                   const float* __restrict__ fcb,
                                                   unsigned short* __restrict__ weff,
                                                   float* __restrict__ cc,
                                                   float* __restrict__ wsum) {
    int o = blockIdx.x;
    int tid = threadIdx.x;
    if (o >= 1000) {
        ushort8 z = {0, 0, 0, 0, 0, 0, 0, 0};
        ((ushort8*)(weff + (size_t)o * 2048))[tid] = z;
        if (tid == 0) { cc[o] = 0.f; wsum[o] = 0.f; }
        return;
    }
    const float* wrow = fcW + (size_t)o * 4096;
    int j0 = tid * 8;
    floatx4 wa  = *(const floatx4*)(wrow + j0);
    floatx4 wb  = *(const floatx4*)(wrow + j0 + 4);
    floatx4 wa2 = *(const floatx4*)(wrow + 2048 + j0);
    floatx4 wb2 = *(const floatx4*)(wrow + 2048 + j0 + 4);
    floatx4 ga  = *(const floatx4*)(lng + j0);
    floatx4 gb  = *(const floatx4*)(lng + j0 + 4);
    floatx4 ga2 = *(const floatx4*)(lng + 2048 + j0);
    floatx4 gb2 = *(const floatx4*)(lng + 2048 + j0 + 4);
    floatx4 ba  = *(const floatx4*)(lnb + j0);
    floatx4 bb  = *(const floatx4*)(lnb + j0 + 4);
    floatx4 ba2 = *(const floatx4*)(lnb + 2048 + j0);
    floatx4 bb2 = *(const floatx4*)(lnb + 2048 + j0 + 4);
    ushort8 o8;
    float acc = 0.f, ws = 0.f;
#pragma unroll
    for (int j = 0; j < 4; ++j) {
        o8[j] = f2bf(ga[j] * wa[j] + ga2[j] * wa2[j]);
        acc += ba[j] * wa[j] + ba2[j] * wa2[j];
        ws  += bf2f(o8[j]);
        o8[4 + j] = f2bf(gb[j] * wb[j] + gb2[j] * wb2[j]);
        acc += bb[j] * wb[j] + bb2[j] * wb2[j];
        ws  += bf2f(o8[4 + j]);
    }
    ((ushort8*)(weff + (size_t)o * 2048))[tid] = o8;
#pragma unroll
    for (int d = 32; d; d >>= 1) { acc += __shfl_down(acc, d); ws += __shfl_down(ws, d); }
    __shared__ float red[4], redw[4];
    if ((tid & 63) == 0) { red[tid >> 6] = acc; redw[tid >> 6] = ws; }
    __syncthreads();
    if (tid == 0) {
        cc[o] = fcb[o] + red[0] + red[1] + red[2] + red[3];
        wsum[o] = redw[0] + redw[1] + redw[2] + redw[3];
    }
}

// -------- row LN stats: mur[row] = {mu, rsqrt(var+eps)} over h2 row -------
__global__ __launch_bounds__(256) void ln_stats(const unsigned short* __restrict__ h2,
                                                float2* __restrict__ mur) {
    int row = blockIdx.x, tid = threadIdx.x;
    ushort8 v = ((const ushort8*)(h2 + (size_t)row * 2048))[tid];
    float s = 0.f, s2 = 0.f;
#pragma unroll
    for (int j = 0; j < 8; ++j) { float f = bf2f(v[j]); s += f; s2 += f * f; }
#pragma unroll
    for (int d = 32; d; d >>= 1) { s += __shfl_down(s, d); s2 += __shfl_down(s2, d); }
    __shared__ float rs_[4], rs2_[4];
    if ((tid & 63) == 0) { rs_[tid >> 6] = s; rs2_[tid >> 6] = s2; }
    __syncthreads();
    if (tid == 0) {
        float S = rs_[0] + rs_[1] + rs_[2] + rs_[3];
        float S2 = rs2_[0] + rs2_[1] + rs2_[2] + rs2_[3];
        float mu = S * (1.f / 2048.f);
        float var = S2 * (1.f / 2048.f) - mu * mu;
        mur[row] = make_float2(mu, rsqrtf(var + 1e-5f));
    }
}

// == reg-pipelined bf16 GEMM: C[M,N] = A[M,K]*B[N,K]^T, BK=64, 3 LDS bufs ==
// BM=128, BN=64*NJ, 512 threads (8 waves 2M x 4N), per-wave C = 64 x 16*NJ.
// Cross-tile register double-buffer: MFMA tile t from set X while ds_reads
// for tile t+1 fill set Y (no consumer this iter -> LDS pipe runs under the
// MFMA burst). Counted vmcnt keeps one tile's stage loads in flight across
// the barrier. LDS layout + swizzle identical to round 4 (0 conflicts):
// 128B rows, byte ^= (row&7)<<4 on both sides.
// EPI 0: bf16 out = tanh(acc + bias0[n] + bias1[n]), stride N
// EPI 1: f32 out = mur[row].y*(acc - mur[row].x*wsum[col]) + bias0[col]
template <int EPI, int NJ>
__global__ __launch_bounds__(512, 2) void gemm_rp(const unsigned short* __restrict__ A,
                                                  const unsigned short* __restrict__ B,
                                                  int M, int N, int K,
                                                  const float* __restrict__ bias0,
                                                  const float* __restrict__ bias1,
                                                  void* __restrict__ Cout, int ncols,
                                                  const float2* __restrict__ mur,
                                                  const float* __restrict__ wsum) {
    extern __shared__ char smem[];
    constexpr int BUFSZ = 16384 + NJ * 8192;   // A (16KB) + B (NJ*8KB), BK=64
    const int tid = threadIdx.x;
    const int lane = tid & 63, wid = tid >> 6;
    const int wm = wid >> 2, wn = wid & 3;      // 2 x 4 wave grid
    const int fr = lane & 15, g = lane >> 4;

    // XCD-aware bijective swizzle (nwg % 8 == 0 for all our launches)
    const int nwg = gridDim.x * gridDim.y;
    const int fid = blockIdx.y * gridDim.x + blockIdx.x;
    const int cpx = nwg >> 3;
    const int sw = (fid & 7) * cpx + (fid >> 3);
    const int bx = sw % gridDim.x, by = sw / gridDim.x;
    const int row0 = by * 128, col0 = bx * (64 * NJ);

    // staging: thread t covers dest byte d = round*8192 + t*16 (linear LDS).
    // logical row = d>>7, col-byte = (d&127) ^ ((row&7)<<4)  (involution)
    const int tg = tid >> 3;                              // row within 64-row round
    const int tcE = ((tid & 7) ^ (tg & 7)) * 8;           // element offset in row

    auto stage = [&](int kt, char* buf) {
#pragma unroll
        for (int r = 0; r < 2; ++r)
            gload_lds16(A + (size_t)(row0 + r * 64 + tg) * K + kt * 64 + tcE,
                        buf + r * 8192 + wid * 1024);
#pragma unroll
        for (int rr = 0; rr < NJ; ++rr)
            gload_lds16(B + (size_t)(col0 + rr * 64 + tg) * K + kt * 64 + tcE,
                        buf + 16384 + rr * 8192 + wid * 1024);
    };

    // swizzled fragment reads
    const int xorv = (fr & 7) << 4;
    auto readFrags = [&](bf16x8 (&fa)[4][2], bf16x8 (&fb)[NJ][2], const char* buf) {
#pragma unroll
        for (int m = 0; m < 4; ++m)
#pragma unroll
            for (int kh = 0; kh < 2; ++kh)
                fa[m][kh] = __builtin_bit_cast(bf16x8, *(const ushort8*)(
                    buf + (wm * 64 + m * 16 + fr) * 128 + ((kh * 64 + g * 16) ^ xorv)));
#pragma unroll
        for (int n = 0; n < NJ; ++n)
#pragma unroll
            for (int kh = 0; kh < 2; ++kh)
                fb[n][kh] = __builtin_bit_cast(bf16x8, *(const ushort8*)(
                    buf + 16384 + (wn * (16 * NJ) + n * 16 + fr) * 128 + ((kh * 64 + g * 16) ^ xorv)));
    };

    f32x4 acc[4][NJ];
#pragma unroll
    for (int i = 0; i < 4; ++i)
#pragma unroll
        for (int j = 0; j < NJ; ++j) acc[i][j] = f32x4{0.f, 0.f, 0.f, 0.f};

    auto domfma = [&](bf16x8 (&fa)[4][2], bf16x8 (&fb)[NJ][2]) {
        __builtin_amdgcn_s_setprio(1);
#pragma unroll
        for (int m = 0; m < 4; ++m)
#pragma unroll
            for (int n = 0; n < NJ; ++n)
#pragma unroll
                for (int kh = 0; kh < 2; ++kh)
                    acc[m][n] = __builtin_amdgcn_mfma_f32_16x16x32_bf16(fa[m][kh], fb[n][kh], acc[m][n], 0, 0, 0);
        __builtin_amdgcn_s_setprio(0);
    };

    bf16x8 aX[4][2], bX[NJ][2], aY[4][2], bY[NJ][2];

    // prologue: stage tiles 0,1; read frags(0) -> set X
    stage(0, smem); stage(1, smem + BUFSZ);
    if constexpr (NJ == 4) VMW(6); else VMW(4);   // tile 0 landed, tile 1 in flight
    BAR();
    readFrags(aX, bX, smem);

    const int NT = K >> 6;   // always even here
    for (int t = 0; t < NT; t += 2) {
        // ---- tile t (set X); read frags(t+1) -> set Y under the MFMAs ----
        if (t + 2 < NT) {
            stage(t + 2, smem + ((t + 2) % 3) * BUFSZ);
            if constexpr (NJ == 4) VMW(6); else VMW(4);   // t+1 landed
        } else {
            VMW(0);
        }
        BAR();
        readFrags(aY, bY, smem + ((t + 1) % 3) * BUFSZ);
        domfma(aX, bX);

        // ---- tile t+1 (set Y); read frags(t+2) -> set X ----
        if (t + 2 < NT) {
            if (t + 3 < NT) {
                stage(t + 3, smem + ((t + 3) % 3) * BUFSZ);
                if constexpr (NJ == 4) VMW(6); else VMW(4);   // t+2 landed
            } else {
                VMW(0);
            }
            BAR();
            readFrags(aX, bX, smem + ((t + 2) % 3) * BUFSZ);
        }
        domfma(aY, bY);
    }

    // ---- epilogue ----
#pragma unroll
    for (int i = 0; i < 4; ++i) {
        int rbase = row0 + wm * 64 + i * 16 + g * 4;
        if (EPI == 0) {
#pragma unroll
            for (int j = 0; j < NJ; ++j) {
                int col = col0 + wn * (16 * NJ) + j * 16 + fr;
                float bsum = bias0[col] + bias1[col];
                unsigned short* O = (unsigned short*)Cout;
#pragma unroll
                for (int r = 0; r < 4; ++r)
                    O[(size_t)(rbase + r) * N + col] = f2bf(tanhf(acc[i][j][r] + bsum));
            }
        } else {
            float2 mr[4];
#pragma unroll
            for (int r = 0; r < 4; ++r) mr[r] = mur[rbase + r];
#pragma unroll
            for (int j = 0; j < NJ; ++j) {
                int col = col0 + wn * (16 * NJ) + j * 16 + fr;
                if (col < ncols) {
                    float ws = wsum[col];
                    float ccv = bias0[col];
                    float* O = (float*)Cout;
#pragma unroll
                    for (int r = 0; r < 4; ++r)
                        O[(size_t)(rbase + r) * ncols + col] =
                            mr[r].y * (acc[i][j][r] - mr[r].x * ws) + ccv;
                }
            }
        }
    }
}

extern "C" void kernel_launch(void* const* d_in, const int* in_sizes, int n_in,
                              void* d_out, int out_size, void* d_ws, size_t ws_size,
                              hipStream_t stream) {
    const float* x   = (const float*)d_in[0];
    const float* W0  = (const float*)d_in[1];
    const float* bi0 = (const float*)d_in[2];
    const float* bh0 = (const float*)d_in[3];
    const float* W1  = (const float*)d_in[4];
    const float* bi1 = (const float*)d_in[5];
    const float* bh1 = (const float*)d_in[6];
    const float* lng = (const float*)d_in[7];
    const float* lnb = (const float*)d_in[8];
    const float* fcW = (const float*)d_in[9];
    const float* fcb = (const float*)d_in[10];
    float* out = (float*)d_out;

    char* w = (char*)d_ws;
    unsigned short* xb   = (unsigned short*)(w);                  // 4096x4096 bf16
    unsigned short* w0b  = (unsigned short*)(w + 33554432ull);    // 2048x4096 bf16
    unsigned short* w1b  = (unsigned short*)(w + 50331648ull);    // 2048x2048 bf16
    unsigned short* h1   = (unsigned short*)(w + 58720256ull);    // 4096x2048 bf16
    unsigned short* h2   = (unsigned short*)(w + 75497472ull);    // 4096x2048 bf16
    unsigned short* weff = (unsigned short*)(w + 92274688ull);    // 1024x2048 bf16
    float* cc            = (float*)(w + 96468992ull);             // 1024 f32
    float* wsum          = (float*)(w + 96473088ull);             // 1024 f32
    float2* mur          = (float2*)(w + 96477184ull);            // 4096 float2

    const int SHM0 = 3 * (16384 + 4 * 8192);  // 147456
    const int SHM1 = 3 * (16384 + 2 * 8192);  // 98304
    (void)hipFuncSetAttribute((const void*)gemm_rp<0, 4>,
                              hipFuncAttributeMaxDynamicSharedMemorySize, SHM0);
    (void)hipFuncSetAttribute((const void*)gemm_rp<1, 2>,
                              hipFuncAttributeMaxDynamicSharedMemorySize, SHM1);

    cvt_f2bf<<<8192, 256, 0, stream>>>(x,  xb,  2097152);
    cvt_f2bf<<<4096, 256, 0, stream>>>(W0, w0b, 1048576);
    cvt_f2bf<<<2048, 256, 0, stream>>>(W1, w1b, 524288);
    weff_kernel<<<1024, 256, 0, stream>>>(fcW, lng, lnb, fcb, weff, cc, wsum);
    // h1 = tanh(x @ W0^T + b_ih0 + b_hh0)
    gemm_rp<0, 4><<<dim3(8, 32), 512, SHM0, stream>>>(xb, w0b, 4096, 2048, 4096,
                                                      bi0, bh0, h1, 2048, nullptr, nullptr);
    // h2 = tanh(h1 @ W1^T + b_ih1 + b_hh1)
    gemm_rp<0, 4><<<dim3(8, 32), 512, SHM0, stream>>>(h1, w1b, 4096, 2048, 2048,
                                                      bi1, bh1, h2, 2048, nullptr, nullptr);
    // per-row LN stats of h2 (concat duplicates -> stats over h2 row)
    ln_stats<<<4096, 256, 0, stream>>>(h2, mur);
    // out = r*(h2 @ Weff^T - mu*wsum) + cc   (LN folded into epilogue)
    gemm_rp<1, 2><<<dim3(8, 32), 512, SHM1, stream>>>(h2, weff, 4096, 1024, 2048,
                                                      cc, nullptr, out, 1000, mur, wsum);
}